// Round 1
// baseline (4332.585 us; speedup 1.0000x reference)
//
#include <hip/hip_runtime.h>
#include <hip/hip_bf16.h>

#define DH 20          // hidden width
#define LANES 32       // lanes per node (f = lane, 20 active)

// ---------------- setup kernels ----------------

__global__ void init_deg(int* __restrict__ out_deg, int* __restrict__ in_deg, int n) {
    int i = blockIdx.x * blockDim.x + threadIdx.x;
    if (i < n) { out_deg[i] = 1; in_deg[i] = 1; }   // self-loop contributes 1 to each
}

__global__ void count_deg(const int* __restrict__ src, const int* __restrict__ dst,
                          int* __restrict__ out_deg, int* __restrict__ in_deg, int E) {
    int e = blockIdx.x * blockDim.x + threadIdx.x;
    if (e < E) {
        atomicAdd(&out_deg[src[e]], 1);
        atomicAdd(&in_deg[dst[e]], 1);
    }
}

__global__ void compute_norm(const int* __restrict__ out_deg, const int* __restrict__ in_deg,
                             double* __restrict__ dout, double* __restrict__ din, int n) {
    int i = blockIdx.x * blockDim.x + threadIdx.x;
    if (i < n) {
        dout[i] = 1.0 / sqrt((double)out_deg[i]);
        din[i]  = 1.0 / sqrt((double)in_deg[i]);
    }
}

// Single-block exclusive scan of (in_deg[i]-1) -> row_ptr, cursor
__global__ void build_rowptr(const int* __restrict__ in_deg, int* __restrict__ row_ptr,
                             int* __restrict__ cursor, int n_nodes, int n_edges) {
    __shared__ int lds[1024];
    int t = threadIdx.x;
    int chunk = (n_nodes + 1023) / 1024;
    int lo = t * chunk;
    int hi = lo + chunk; if (hi > n_nodes) hi = n_nodes;
    int s = 0;
    for (int i = lo; i < hi; ++i) s += in_deg[i] - 1;
    lds[t] = s;
    __syncthreads();
    // Hillis-Steele inclusive scan over 1024 partials
    for (int off = 1; off < 1024; off <<= 1) {
        int v = (t >= off) ? lds[t - off] : 0;
        __syncthreads();
        lds[t] += v;
        __syncthreads();
    }
    int run = lds[t] - s;   // exclusive prefix of this chunk
    for (int i = lo; i < hi; ++i) {
        row_ptr[i] = run;
        cursor[i]  = run;
        run += in_deg[i] - 1;
    }
    if (t == 0) row_ptr[n_nodes] = n_edges;
}

__global__ void fill_csr(const int* __restrict__ src, const int* __restrict__ dst,
                         int* __restrict__ cursor, int* __restrict__ col, int E) {
    int e = blockIdx.x * blockDim.x + threadIdx.x;
    if (e < E) {
        int slot = atomicAdd(&cursor[dst[e]], 1);
        col[slot] = src[e];
    }
}

// ---------------- per-layer kernels ----------------

// hw[n][j] = dout[n] * feat[n] * W_start[j]    (D_in = 1)
__global__ __launch_bounds__(256) void transform_start(
        const float* __restrict__ feat, const float* __restrict__ W,
        const double* __restrict__ dout, float* __restrict__ hw, int n_nodes) {
    int gid = blockIdx.x * blockDim.x + threadIdx.x;
    int n = gid >> 5, j = gid & (LANES - 1);
    if (n >= n_nodes || j >= DH) return;
    hw[n * DH + j] = (float)((double)feat[n] * dout[n] * (double)W[j]);
}

// hw[n][j] = dout[n] * sum_k h[n][k] * W[k][j]
__global__ __launch_bounds__(256) void transform_mid(
        const float* __restrict__ h, const float* __restrict__ W,
        const double* __restrict__ dout, float* __restrict__ hw, int n_nodes) {
    int gid = blockIdx.x * blockDim.x + threadIdx.x;
    int n = gid >> 5, j = gid & (LANES - 1);
    if (n >= n_nodes || j >= DH) return;
    const float* hr = h + (long)n * DH;
    double acc = 0.0;
#pragma unroll
    for (int k = 0; k < DH; ++k)
        acc += (double)hr[k] * (double)W[k * DH + j];
    hw[n * DH + j] = (float)(acc * dout[n]);
}

// out[n][j] = (relu?) din[n]*(hw[n][j] + sum_{e in row n} hw[col[e]][j]) + b[j]
__global__ __launch_bounds__(256) void aggregate(
        const float* __restrict__ hw, const int* __restrict__ row_ptr,
        const int* __restrict__ col, const double* __restrict__ din,
        const float* __restrict__ b, float* __restrict__ out,
        int n_nodes, int do_relu) {
    int gid = blockIdx.x * blockDim.x + threadIdx.x;
    int n = gid >> 5, j = gid & (LANES - 1);
    if (n >= n_nodes || j >= DH) return;
    double acc = (double)hw[n * DH + j];     // self-loop edge
    int e0 = row_ptr[n], e1 = row_ptr[n + 1];
    for (int e = e0; e < e1; ++e) {
        int s = col[e];
        acc += (double)hw[s * DH + j];
    }
    float v = (float)(acc * din[n] + (double)b[j]);
    if (do_relu) v = fmaxf(v, 0.0f);
    out[n * DH + j] = v;
}

// ---------------- launch ----------------

static inline size_t align256(size_t x) { return (x + 255) & ~(size_t)255; }

extern "C" void kernel_launch(void* const* d_in, const int* in_sizes, int n_in,
                              void* d_out, int out_size, void* d_ws, size_t ws_size,
                              hipStream_t stream) {
    const float* feat    = (const float*)d_in[0];
    const float* W_start = (const float*)d_in[1];
    const float* b_start = (const float*)d_in[2];
    const float* W_mid   = (const float*)d_in[3];
    const float* b_mid   = (const float*)d_in[4];
    const float* W_final = (const float*)d_in[5];
    const float* b_final = (const float*)d_in[6];
    const int*   src     = (const int*)d_in[7];
    const int*   dst     = (const int*)d_in[8];

    const int N = in_sizes[0];          // 100000
    const int E = in_sizes[7];          // 3200000
    const int L = in_sizes[3] / (DH * DH);  // 18 mid layers

    // workspace carve-up
    char* p = (char*)d_ws;
    double* dout_d = (double*)p; p += align256(sizeof(double) * N);
    double* din_d  = (double*)p; p += align256(sizeof(double) * N);
    int* out_deg   = (int*)p;    p += align256(sizeof(int) * N);
    int* in_deg    = (int*)p;    p += align256(sizeof(int) * N);
    int* row_ptr   = (int*)p;    p += align256(sizeof(int) * (N + 1));
    int* cursor    = (int*)p;    p += align256(sizeof(int) * N);
    int* col       = (int*)p;    p += align256(sizeof(int) * E);
    float* hw      = (float*)p;  p += align256(sizeof(float) * N * DH);
    float* hbuf    = (float*)p;  p += align256(sizeof(float) * N * DH);

    const int BT = 256;
    int grid_n  = (N + BT - 1) / BT;
    int grid_e  = (E + BT - 1) / BT;
    int grid_nf = (N * LANES + BT - 1) / BT;

    // ---- graph setup (identical work every call) ----
    init_deg<<<grid_n, BT, 0, stream>>>(out_deg, in_deg, N);
    count_deg<<<grid_e, BT, 0, stream>>>(src, dst, out_deg, in_deg, E);
    compute_norm<<<grid_n, BT, 0, stream>>>(out_deg, in_deg, dout_d, din_d, N);
    build_rowptr<<<1, 1024, 0, stream>>>(in_deg, row_ptr, cursor, N, E);
    fill_csr<<<grid_e, BT, 0, stream>>>(src, dst, cursor, col, E);

    // ---- layer 0: feat (N x 1) -> hbuf ----
    transform_start<<<grid_nf, BT, 0, stream>>>(feat, W_start, dout_d, hw, N);
    aggregate<<<grid_nf, BT, 0, stream>>>(hw, row_ptr, col, din_d, b_start, hbuf, N, 1);

    // ---- 18 mid layers ----
    for (int l = 0; l < L; ++l) {
        transform_mid<<<grid_nf, BT, 0, stream>>>(hbuf, W_mid + (size_t)l * DH * DH,
                                                  dout_d, hw, N);
        aggregate<<<grid_nf, BT, 0, stream>>>(hw, row_ptr, col, din_d,
                                              b_mid + (size_t)l * DH, hbuf, N, 1);
    }

    // ---- final layer: no relu, write d_out ----
    transform_mid<<<grid_nf, BT, 0, stream>>>(hbuf, W_final, dout_d, hw, N);
    aggregate<<<grid_nf, BT, 0, stream>>>(hw, row_ptr, col, din_d, b_final,
                                          (float*)d_out, N, 0);
}

// Round 2
// 2853.894 us; speedup vs baseline: 1.5181x; 1.5181x over previous
//
#include <hip/hip_runtime.h>
#include <hip/hip_bf16.h>

#define DH 20          // hidden width
// mapping: 32 lanes per node, lane j = output feature (20 active)

// ---------------- setup kernels ----------------

__global__ void init_deg(int* __restrict__ out_deg, int* __restrict__ in_deg, int n) {
    int i = blockIdx.x * blockDim.x + threadIdx.x;
    if (i < n) { out_deg[i] = 1; in_deg[i] = 1; }   // self-loop contributes 1 to each
}

__global__ void count_deg(const int* __restrict__ src, const int* __restrict__ dst,
                          int* __restrict__ out_deg, int* __restrict__ in_deg, int E) {
    int e = blockIdx.x * blockDim.x + threadIdx.x;
    if (e < E) {
        atomicAdd(&out_deg[src[e]], 1);
        atomicAdd(&in_deg[dst[e]], 1);
    }
}

__global__ void compute_norm(const int* __restrict__ out_deg, const int* __restrict__ in_deg,
                             double* __restrict__ dout, double* __restrict__ din, int n) {
    int i = blockIdx.x * blockDim.x + threadIdx.x;
    if (i < n) {
        dout[i] = 1.0 / sqrt((double)out_deg[i]);
        din[i]  = 1.0 / sqrt((double)in_deg[i]);
    }
}

// Single-block exclusive scan of (in_deg[i]-1) -> row_ptr, cursor
__global__ void build_rowptr(const int* __restrict__ in_deg, int* __restrict__ row_ptr,
                             int* __restrict__ cursor, int n_nodes, int n_edges) {
    __shared__ int lds[1024];
    int t = threadIdx.x;
    int chunk = (n_nodes + 1023) / 1024;
    int lo = t * chunk;
    int hi = lo + chunk; if (hi > n_nodes) hi = n_nodes;
    int s = 0;
    for (int i = lo; i < hi; ++i) s += in_deg[i] - 1;
    lds[t] = s;
    __syncthreads();
    for (int off = 1; off < 1024; off <<= 1) {
        int v = (t >= off) ? lds[t - off] : 0;
        __syncthreads();
        lds[t] += v;
        __syncthreads();
    }
    int run = lds[t] - s;   // exclusive prefix of this chunk
    for (int i = lo; i < hi; ++i) {
        row_ptr[i] = run;
        cursor[i]  = run;
        run += in_deg[i] - 1;
    }
    if (t == 0) row_ptr[n_nodes] = n_edges;
}

__global__ void fill_csr(const int* __restrict__ src, const int* __restrict__ dst,
                         int* __restrict__ cursor, int* __restrict__ col, int E) {
    int e = blockIdx.x * blockDim.x + threadIdx.x;
    if (e < E) {
        int slot = atomicAdd(&cursor[dst[e]], 1);
        col[slot] = src[e];
    }
}

// ---------------- layer kernels (aggregate-first formulation) ----------------

// x0[n] = feat[n] * dout[n]   (layer 0 input is N x 1)
__global__ void compute_x0(const float* __restrict__ feat, const double* __restrict__ dout,
                           double* __restrict__ x0, int n) {
    int i = blockIdx.x * blockDim.x + threadIdx.x;
    if (i < n) x0[i] = (double)feat[i] * dout[i];
}

// layer 0: g[n] = x0[n] + sum_{s in N(n)} x0[s]  (scalar gather)
// xout[n][j] = relu(din[n]*g[n]*W[j] + b[j]) * dout[n]
__global__ __launch_bounds__(256) void layer_start(
        const double* __restrict__ x0, const int* __restrict__ row_ptr,
        const int* __restrict__ col, const double* __restrict__ din,
        const double* __restrict__ dout, const float* __restrict__ W,
        const float* __restrict__ b, float* __restrict__ xout, int n_nodes) {
    int gid = blockIdx.x * blockDim.x + threadIdx.x;
    int n = gid >> 5, j = gid & 31;
    if (n >= n_nodes) return;
    double g = x0[n];                       // self loop
    int e0 = row_ptr[n], e1 = row_ptr[n + 1];
    int e = e0;
    double g1 = 0.0;
    for (; e + 1 < e1; e += 2) {
        int s0 = col[e], s1 = col[e + 1];
        g  += x0[s0];
        g1 += x0[s1];
    }
    if (e < e1) g += x0[col[e]];
    g += g1;
    if (j < DH) {
        double v = g * din[n] * (double)W[j] + (double)b[j];
        float r = fmaxf((float)v, 0.0f);
        xout[(long)n * DH + j] = (float)((double)r * dout[n]);
    }
}

// mid/final layers, fused gather + matvec:
//   g_j[n] = x[n][j] + sum_{s in N(n)} x[s][j]          (x = h * dout, fp32)
//   out_j  = din[n] * sum_k g_k W[k][j] + b[j]
//   mode 0: store relu(out)*dout[n]   (feeds next layer)
//   mode 1: store out raw             (network output)
__global__ __launch_bounds__(256) void layer_mid(
        const float* __restrict__ x, const int* __restrict__ row_ptr,
        const int* __restrict__ col, const double* __restrict__ din,
        const double* __restrict__ dout, const float* __restrict__ W,
        const float* __restrict__ b, float* __restrict__ xout,
        int n_nodes, int mode) {
    __shared__ float Wl[DH * DH + 16];      // padded so lanes j>=20 read in-bounds
    for (int i = threadIdx.x; i < DH * DH + 16; i += blockDim.x)
        Wl[i] = (i < DH * DH) ? W[i] : 0.0f;
    __syncthreads();

    int gid = blockIdx.x * blockDim.x + threadIdx.x;
    int n = gid >> 5, j = gid & 31;
    if (n >= n_nodes) return;

    double a0 = 0.0, a1 = 0.0;
    if (j < DH) {
        a0 = (double)x[(long)n * DH + j];   // self loop
        int e0 = row_ptr[n], e1 = row_ptr[n + 1];
        int e = e0;
        for (; e + 1 < e1; e += 2) {
            int s0 = col[e], s1 = col[e + 1];
            float v0 = x[(long)s0 * DH + j];
            float v1 = x[(long)s1 * DH + j];
            a0 += (double)v0;
            a1 += (double)v1;
        }
        if (e < e1) a0 += (double)x[(long)col[e] * DH + j];
    }
    double g = a0 + a1;

    // cross-lane matvec within the 32-lane node group
    double acc = 0.0;
#pragma unroll
    for (int k = 0; k < DH; ++k) {
        double gk = __shfl(g, k, 32);
        acc += gk * (double)Wl[k * DH + j];
    }
    if (j < DH) {
        double v = acc * din[n] + (double)b[j];
        if (mode == 0) {
            float r = fmaxf((float)v, 0.0f);
            xout[(long)n * DH + j] = (float)((double)r * dout[n]);
        } else {
            xout[(long)n * DH + j] = (float)v;
        }
    }
}

// ---------------- launch ----------------

static inline size_t align256(size_t x) { return (x + 255) & ~(size_t)255; }

extern "C" void kernel_launch(void* const* d_in, const int* in_sizes, int n_in,
                              void* d_out, int out_size, void* d_ws, size_t ws_size,
                              hipStream_t stream) {
    const float* feat    = (const float*)d_in[0];
    const float* W_start = (const float*)d_in[1];
    const float* b_start = (const float*)d_in[2];
    const float* W_mid   = (const float*)d_in[3];
    const float* b_mid   = (const float*)d_in[4];
    const float* W_final = (const float*)d_in[5];
    const float* b_final = (const float*)d_in[6];
    const int*   src     = (const int*)d_in[7];
    const int*   dst     = (const int*)d_in[8];

    const int N = in_sizes[0];              // 100000
    const int E = in_sizes[7];              // 3200000
    const int L = in_sizes[3] / (DH * DH);  // 18 mid layers

    // workspace carve-up
    char* p = (char*)d_ws;
    double* dout_d = (double*)p; p += align256(sizeof(double) * N);
    double* din_d  = (double*)p; p += align256(sizeof(double) * N);
    double* x0     = (double*)p; p += align256(sizeof(double) * N);
    int* out_deg   = (int*)p;    p += align256(sizeof(int) * N);
    int* in_deg    = (int*)p;    p += align256(sizeof(int) * N);
    int* row_ptr   = (int*)p;    p += align256(sizeof(int) * (N + 1));
    int* cursor    = (int*)p;    p += align256(sizeof(int) * N);
    int* col       = (int*)p;    p += align256(sizeof(int) * E);
    float* xa      = (float*)p;  p += align256(sizeof(float) * N * DH);
    float* xb      = (float*)p;  p += align256(sizeof(float) * N * DH);

    const int BT = 256;
    int grid_n  = (N + BT - 1) / BT;
    int grid_e  = (E + BT - 1) / BT;
    int grid_nf = (N * 32 + BT - 1) / BT;

    // ---- graph setup (identical work every call) ----
    init_deg<<<grid_n, BT, 0, stream>>>(out_deg, in_deg, N);
    count_deg<<<grid_e, BT, 0, stream>>>(src, dst, out_deg, in_deg, E);
    compute_norm<<<grid_n, BT, 0, stream>>>(out_deg, in_deg, dout_d, din_d, N);
    build_rowptr<<<1, 1024, 0, stream>>>(in_deg, row_ptr, cursor, N, E);
    fill_csr<<<grid_e, BT, 0, stream>>>(src, dst, cursor, col, E);

    // ---- layer 0 (scalar input) ----
    compute_x0<<<grid_n, BT, 0, stream>>>(feat, dout_d, x0, N);
    layer_start<<<grid_nf, BT, 0, stream>>>(x0, row_ptr, col, din_d, dout_d,
                                            W_start, b_start, xa, N);

    // ---- 18 mid layers (ping-pong xa/xb) ----
    float* xin = xa;
    float* xot = xb;
    for (int l = 0; l < L; ++l) {
        layer_mid<<<grid_nf, BT, 0, stream>>>(xin, row_ptr, col, din_d, dout_d,
                                              W_mid + (size_t)l * DH * DH,
                                              b_mid + (size_t)l * DH, xot, N, 0);
        float* t = xin; xin = xot; xot = t;
    }

    // ---- final layer: raw store to d_out ----
    layer_mid<<<grid_nf, BT, 0, stream>>>(xin, row_ptr, col, din_d, dout_d,
                                          W_final, b_final, (float*)d_out, N, 1);
}

// Round 3
// 2716.623 us; speedup vs baseline: 1.5948x; 1.0505x over previous
//
#include <hip/hip_runtime.h>
#include <hip/hip_bf16.h>

#define DH 20          // hidden width

// ---------------- setup kernels ----------------

__global__ void init_deg(int* __restrict__ out_deg, int* __restrict__ in_deg, int n) {
    int i = blockIdx.x * blockDim.x + threadIdx.x;
    if (i < n) { out_deg[i] = 1; in_deg[i] = 1; }   // self-loop contributes 1 to each
}

__global__ void count_deg(const int* __restrict__ src, const int* __restrict__ dst,
                          int* __restrict__ out_deg, int* __restrict__ in_deg, int E) {
    int e = blockIdx.x * blockDim.x + threadIdx.x;
    if (e < E) {
        atomicAdd(&out_deg[src[e]], 1);
        atomicAdd(&in_deg[dst[e]], 1);
    }
}

__global__ void compute_norm(const int* __restrict__ out_deg, const int* __restrict__ in_deg,
                             double* __restrict__ dout, double* __restrict__ din, int n) {
    int i = blockIdx.x * blockDim.x + threadIdx.x;
    if (i < n) {
        dout[i] = 1.0 / sqrt((double)out_deg[i]);
        din[i]  = 1.0 / sqrt((double)in_deg[i]);
    }
}

// Single-block exclusive scan of (in_deg[i]-1) -> row_ptr, cursor
__global__ void build_rowptr(const int* __restrict__ in_deg, int* __restrict__ row_ptr,
                             int* __restrict__ cursor, int n_nodes, int n_edges) {
    __shared__ int lds[1024];
    int t = threadIdx.x;
    int chunk = (n_nodes + 1023) / 1024;
    int lo = t * chunk;
    int hi = lo + chunk; if (hi > n_nodes) hi = n_nodes;
    int s = 0;
    for (int i = lo; i < hi; ++i) s += in_deg[i] - 1;
    lds[t] = s;
    __syncthreads();
    for (int off = 1; off < 1024; off <<= 1) {
        int v = (t >= off) ? lds[t - off] : 0;
        __syncthreads();
        lds[t] += v;
        __syncthreads();
    }
    int run = lds[t] - s;   // exclusive prefix of this chunk
    for (int i = lo; i < hi; ++i) {
        row_ptr[i] = run;
        cursor[i]  = run;
        run += in_deg[i] - 1;
    }
    if (t == 0) row_ptr[n_nodes] = n_edges;
}

__global__ void fill_csr(const int* __restrict__ src, const int* __restrict__ dst,
                         int* __restrict__ cursor, int* __restrict__ col, int E) {
    int e = blockIdx.x * blockDim.x + threadIdx.x;
    if (e < E) {
        int slot = atomicAdd(&cursor[dst[e]], 1);
        col[slot] = src[e];
    }
}

// ---------------- layer kernels (aggregate-first, 1 wave per node) ----------------

// x0[n] = feat[n] * dout[n]   (layer 0 input is N x 1)
__global__ void compute_x0(const float* __restrict__ feat, const double* __restrict__ dout,
                           double* __restrict__ x0, int n) {
    int i = blockIdx.x * blockDim.x + threadIdx.x;
    if (i < n) x0[i] = (double)feat[i] * dout[i];
}

// layer 0: g[n] = x0[n] + sum_{s in N(n)} x0[s]  (scalar gather, 64 lanes edge-parallel)
// xout[n][j] = relu(din[n]*g[n]*W[j] + b[j]) * dout[n]
__global__ __launch_bounds__(256) void layer_start(
        const double* __restrict__ x0, const int* __restrict__ row_ptr,
        const int* __restrict__ col, const double* __restrict__ din,
        const double* __restrict__ dout, const float* __restrict__ W,
        const float* __restrict__ b, float* __restrict__ xout, int n_nodes) {
    int n    = (blockIdx.x * blockDim.x + threadIdx.x) >> 6;   // one wave per node
    int lane = threadIdx.x & 63;
    if (n >= n_nodes) return;
    double a = (lane == 0) ? x0[n] : 0.0;   // self loop
    int e0 = row_ptr[n], e1 = row_ptr[n + 1];
    for (int e = e0 + lane; e < e1; e += 64)
        a += x0[__builtin_nontemporal_load(&col[e])];
#pragma unroll
    for (int off = 32; off > 0; off >>= 1)
        a += __shfl_xor(a, off, 64);
    if (lane < DH) {
        double v = a * din[n] * (double)W[lane] + (double)b[lane];
        float r = fmaxf((float)v, 0.0f);
        xout[(long)n * DH + lane] = (float)((double)r * dout[n]);
    }
}

// mid/final layers: one wave per node.
// lane = 5*ep + jq,  ep in [0,12) = edge slot, jq in [0,5) = float4 quarter of the row.
//   gather: 12 edges per load instruction, unroll x2 -> 24 edges in flight.
//   reduce over ep via shfl folds, then cross-lane fp64 matvec with W in LDS.
//   mode 0: store relu(out)*dout[n]; mode 1: store out raw (network output).
__global__ __launch_bounds__(256) void layer_mid(
        const float* __restrict__ x, const int* __restrict__ row_ptr,
        const int* __restrict__ col, const double* __restrict__ din,
        const double* __restrict__ dout, const float* __restrict__ W,
        const float* __restrict__ b, float* __restrict__ xout,
        int n_nodes, int mode) {
    __shared__ float Wl[DH * DH];
    for (int i = threadIdx.x; i < DH * DH; i += blockDim.x) Wl[i] = W[i];
    __syncthreads();

    int n    = (blockIdx.x * blockDim.x + threadIdx.x) >> 6;   // one wave per node
    int lane = threadIdx.x & 63;
    if (n >= n_nodes) return;

    int ep = lane / 5;           // edge slot 0..12 (12 for lanes 60..63 -> inactive)
    int jq = lane - ep * 5;      // float4 quarter 0..4
    const float4* __restrict__ x4 = (const float4*)x;   // row n = x4[n*5 .. n*5+4]

    double g[4] = {0.0, 0.0, 0.0, 0.0};
    double b0 = 0.0, b1 = 0.0, b2 = 0.0, b3 = 0.0;

    if (ep == 0) {               // self loop handled by slot 0
        float4 v = x4[n * 5 + jq];
        g[0] = (double)v.x; g[1] = (double)v.y; g[2] = (double)v.z; g[3] = (double)v.w;
    }
    if (ep < 12) {
        int e0 = row_ptr[n], e1 = row_ptr[n + 1];
        int e = e0 + ep;
        for (; e + 12 < e1; e += 24) {
            int s0 = __builtin_nontemporal_load(&col[e]);
            int s1 = __builtin_nontemporal_load(&col[e + 12]);
            float4 v0 = x4[s0 * 5 + jq];
            float4 v1 = x4[s1 * 5 + jq];
            g[0] += (double)v0.x; g[1] += (double)v0.y;
            g[2] += (double)v0.z; g[3] += (double)v0.w;
            b0   += (double)v1.x; b1   += (double)v1.y;
            b2   += (double)v1.z; b3   += (double)v1.w;
        }
        if (e < e1) {
            int s = __builtin_nontemporal_load(&col[e]);
            float4 v = x4[s * 5 + jq];
            g[0] += (double)v.x; g[1] += (double)v.y;
            g[2] += (double)v.z; g[3] += (double)v.w;
        }
    }
    g[0] += b0; g[1] += b1; g[2] += b2; g[3] += b3;

    // fold 12 edge slots down to slot 0 (lanes 0..4 hold g[0..3] = features 4*jq..4*jq+3)
#define FOLD(LIM, DELTA)                                                        \
    {                                                                           \
        int srcl = lane + DELTA; if (srcl > 63) srcl = lane;                    \
        double t0 = __shfl(g[0], srcl, 64);                                     \
        double t1 = __shfl(g[1], srcl, 64);                                     \
        double t2 = __shfl(g[2], srcl, 64);                                     \
        double t3 = __shfl(g[3], srcl, 64);                                     \
        if (ep < (LIM)) { g[0] += t0; g[1] += t1; g[2] += t2; g[3] += t3; }     \
    }
    FOLD(4, 40)   // ep(0..3)  += ep+8
    FOLD(4, 20)   // ep(0..3)  += ep+4
    FOLD(2, 10)   // ep(0..1)  += ep+2
    FOLD(1, 5)    // ep(0)     += ep+1
#undef FOLD

    // cross-lane matvec: out_j = sum_k g_k * W[k][j];  g_k lives at lane k>>2, reg k&3
    int jj = (lane < DH) ? lane : 0;
    double acc = 0.0;
#pragma unroll
    for (int k = 0; k < DH; ++k) {
        double gk = __shfl(g[k & 3], k >> 2, 64);
        acc += gk * (double)Wl[k * DH + jj];
    }

    if (lane < DH) {
        double v = acc * din[n] + (double)b[lane];
        if (mode == 0) {
            float r = fmaxf((float)v, 0.0f);
            xout[(long)n * DH + lane] = (float)((double)r * dout[n]);
        } else {
            xout[(long)n * DH + lane] = (float)v;
        }
    }
}

// ---------------- launch ----------------

static inline size_t align256(size_t x) { return (x + 255) & ~(size_t)255; }

extern "C" void kernel_launch(void* const* d_in, const int* in_sizes, int n_in,
                              void* d_out, int out_size, void* d_ws, size_t ws_size,
                              hipStream_t stream) {
    const float* feat    = (const float*)d_in[0];
    const float* W_start = (const float*)d_in[1];
    const float* b_start = (const float*)d_in[2];
    const float* W_mid   = (const float*)d_in[3];
    const float* b_mid   = (const float*)d_in[4];
    const float* W_final = (const float*)d_in[5];
    const float* b_final = (const float*)d_in[6];
    const int*   src     = (const int*)d_in[7];
    const int*   dst     = (const int*)d_in[8];

    const int N = in_sizes[0];              // 100000
    const int E = in_sizes[7];              // 3200000
    const int L = in_sizes[3] / (DH * DH);  // 18 mid layers

    // workspace carve-up
    char* p = (char*)d_ws;
    double* dout_d = (double*)p; p += align256(sizeof(double) * N);
    double* din_d  = (double*)p; p += align256(sizeof(double) * N);
    double* x0     = (double*)p; p += align256(sizeof(double) * N);
    int* out_deg   = (int*)p;    p += align256(sizeof(int) * N);
    int* in_deg    = (int*)p;    p += align256(sizeof(int) * N);
    int* row_ptr   = (int*)p;    p += align256(sizeof(int) * (N + 1));
    int* cursor    = (int*)p;    p += align256(sizeof(int) * N);
    int* col       = (int*)p;    p += align256(sizeof(int) * E);
    float* xa      = (float*)p;  p += align256(sizeof(float) * N * DH);
    float* xb      = (float*)p;  p += align256(sizeof(float) * N * DH);

    const int BT = 256;
    int grid_n  = (N + BT - 1) / BT;
    int grid_e  = (E + BT - 1) / BT;
    int grid_nw = (N + 3) / 4;              // 1 wave per node, 4 waves per block

    // ---- graph setup (identical work every call) ----
    init_deg<<<grid_n, BT, 0, stream>>>(out_deg, in_deg, N);
    count_deg<<<grid_e, BT, 0, stream>>>(src, dst, out_deg, in_deg, E);
    compute_norm<<<grid_n, BT, 0, stream>>>(out_deg, in_deg, dout_d, din_d, N);
    build_rowptr<<<1, 1024, 0, stream>>>(in_deg, row_ptr, cursor, N, E);
    fill_csr<<<grid_e, BT, 0, stream>>>(src, dst, cursor, col, E);

    // ---- layer 0 (scalar input) ----
    compute_x0<<<grid_n, BT, 0, stream>>>(feat, dout_d, x0, N);
    layer_start<<<grid_nw, BT, 0, stream>>>(x0, row_ptr, col, din_d, dout_d,
                                            W_start, b_start, xa, N);

    // ---- 18 mid layers (ping-pong xa/xb) ----
    float* xin = xa;
    float* xot = xb;
    for (int l = 0; l < L; ++l) {
        layer_mid<<<grid_nw, BT, 0, stream>>>(xin, row_ptr, col, din_d, dout_d,
                                              W_mid + (size_t)l * DH * DH,
                                              b_mid + (size_t)l * DH, xot, N, 0);
        float* t = xin; xin = xot; xot = t;
    }

    // ---- final layer: raw store to d_out ----
    layer_mid<<<grid_nw, BT, 0, stream>>>(xin, row_ptr, col, din_d, dout_d,
                                          W_final, b_final, (float*)d_out, N, 1);
}

// Round 4
// 2594.150 us; speedup vs baseline: 1.6701x; 1.0472x over previous
//
#include <hip/hip_runtime.h>
#include <hip/hip_bf16.h>

#define DH 20          // hidden width

// ---------------- setup kernels ----------------

__global__ void init_deg(int* __restrict__ out_deg, int* __restrict__ in_deg, int n) {
    int i = blockIdx.x * blockDim.x + threadIdx.x;
    if (i < n) { out_deg[i] = 1; in_deg[i] = 1; }   // self-loop contributes 1 to each
}

__global__ void count_deg(const int* __restrict__ src, const int* __restrict__ dst,
                          int* __restrict__ out_deg, int* __restrict__ in_deg, int E) {
    int e = blockIdx.x * blockDim.x + threadIdx.x;
    if (e < E) {
        atomicAdd(&out_deg[src[e]], 1);
        atomicAdd(&in_deg[dst[e]], 1);
    }
}

__global__ void compute_norm(const int* __restrict__ out_deg, const int* __restrict__ in_deg,
                             double* __restrict__ dout, double* __restrict__ din, int n) {
    int i = blockIdx.x * blockDim.x + threadIdx.x;
    if (i < n) {
        dout[i] = 1.0 / sqrt((double)out_deg[i]);
        din[i]  = 1.0 / sqrt((double)in_deg[i]);
    }
}

// Single-block exclusive scan of (in_deg[i]-1) -> row_ptr, cursor
__global__ void build_rowptr(const int* __restrict__ in_deg, int* __restrict__ row_ptr,
                             int* __restrict__ cursor, int n_nodes, int n_edges) {
    __shared__ int lds[1024];
    int t = threadIdx.x;
    int chunk = (n_nodes + 1023) / 1024;
    int lo = t * chunk;
    int hi = lo + chunk; if (hi > n_nodes) hi = n_nodes;
    int s = 0;
    for (int i = lo; i < hi; ++i) s += in_deg[i] - 1;
    lds[t] = s;
    __syncthreads();
    for (int off = 1; off < 1024; off <<= 1) {
        int v = (t >= off) ? lds[t - off] : 0;
        __syncthreads();
        lds[t] += v;
        __syncthreads();
    }
    int run = lds[t] - s;   // exclusive prefix of this chunk
    for (int i = lo; i < hi; ++i) {
        row_ptr[i] = run;
        cursor[i]  = run;
        run += in_deg[i] - 1;
    }
    if (t == 0) row_ptr[n_nodes] = n_edges;
}

__global__ void fill_csr(const int* __restrict__ src, const int* __restrict__ dst,
                         int* __restrict__ cursor, int* __restrict__ col, int E) {
    int e = blockIdx.x * blockDim.x + threadIdx.x;
    if (e < E) {
        int slot = atomicAdd(&cursor[dst[e]], 1);
        col[slot] = src[e];
    }
}

// ---------------- layer kernels (aggregate-first, 1 wave per node) ----------------

// x0[n] = feat[n] * dout[n]   (layer 0 input is N x 1)
__global__ void compute_x0(const float* __restrict__ feat, const double* __restrict__ dout,
                           double* __restrict__ x0, int n) {
    int i = blockIdx.x * blockDim.x + threadIdx.x;
    if (i < n) x0[i] = (double)feat[i] * dout[i];
}

// layer 0: g[n] = x0[n] + sum_{s in N(n)} x0[s]  (scalar gather, 64 lanes edge-parallel)
__global__ __launch_bounds__(256) void layer_start(
        const double* __restrict__ x0, const int* __restrict__ row_ptr,
        const int* __restrict__ col, const double* __restrict__ din,
        const double* __restrict__ dout, const float* __restrict__ W,
        const float* __restrict__ b, float* __restrict__ xout, int n_nodes) {
    int n    = (blockIdx.x * blockDim.x + threadIdx.x) >> 6;   // one wave per node
    int lane = threadIdx.x & 63;
    if (n >= n_nodes) return;
    double a = (lane == 0) ? x0[n] : 0.0;   // self loop
    int e0 = row_ptr[n], e1 = row_ptr[n + 1];
    for (int e = e0 + lane; e < e1; e += 64)
        a += x0[__builtin_nontemporal_load(&col[e])];
#pragma unroll
    for (int off = 32; off > 0; off >>= 1)
        a += __shfl_xor(a, off, 64);
    if (lane < DH) {
        double v = a * din[n] * (double)W[lane] + (double)b[lane];
        float r = fmaxf((float)v, 0.0f);
        xout[(long)n * DH + lane] = (float)((double)r * dout[n]);
    }
}

// mid/final layers: one wave per node, batch gather.
// lane = 5*ep + jq,  ep in [0,12) = edge slot, jq in [0,5) = float4 quarter of the row.
// One coalesced col load covers up to 64 edges; indices distributed by shfl; 4
// independent gathers per lane cover 48 edges with no loop (deg<=48 for ~99.8%
// of Poisson(32) rows); rare tail handled by a loop.
__global__ __launch_bounds__(256, 8) void layer_mid(
        const float* __restrict__ x, const int* __restrict__ row_ptr,
        const int* __restrict__ col, const double* __restrict__ din,
        const double* __restrict__ dout, const float* __restrict__ W,
        const float* __restrict__ b, float* __restrict__ xout,
        int n_nodes, int mode) {
    __shared__ float Wl[DH * DH];
    for (int i = threadIdx.x; i < DH * DH; i += blockDim.x) Wl[i] = W[i];
    __syncthreads();

    int n    = (blockIdx.x * blockDim.x + threadIdx.x) >> 6;   // one wave per node
    int lane = threadIdx.x & 63;
    if (n >= n_nodes) return;

    int ep = lane / 5;           // edge slot 0..12 (lanes 60..63 -> ep=12, inactive slots)
    int jq = lane - ep * 5;      // float4 quarter 0..4
    const float4* __restrict__ x4 = (const float4*)x;   // row n = x4[n*5 .. n*5+4]

    int e0 = row_ptr[n], e1 = row_ptr[n + 1];

    // one coalesced col load: lane <-> edge position e0+lane
    int epos = e0 + lane;
    int ci = -1;
    if (epos < e1) ci = __builtin_nontemporal_load(&col[epos]);

    // distribute indices to edge slots: slot ep takes positions ep, ep+12, ep+24, ep+36
    int s0 = __shfl(ci, ep, 64);
    int s1 = __shfl(ci, ep + 12, 64);
    int s2 = __shfl(ci, ep + 24, 64);
    int s3 = __shfl(ci, ep + 36, 64);
    bool p0 = (ep < 12) && (s0 >= 0);
    bool p1 = (ep < 12) && (s1 >= 0);
    bool p2 = (ep < 12) && (s2 >= 0);
    bool p3 = (ep < 12) && (s3 >= 0);
    // unconditional gathers (invalid slots read the L1-hot self row, masked from the sum)
    float4 v0 = x4[(p0 ? s0 : n) * 5 + jq];
    float4 v1 = x4[(p1 ? s1 : n) * 5 + jq];
    float4 v2 = x4[(p2 ? s2 : n) * 5 + jq];
    float4 v3 = x4[(p3 ? s3 : n) * 5 + jq];

    double g[4] = {0.0, 0.0, 0.0, 0.0};
    if (ep == 0) {               // self loop handled by slot 0
        float4 v = x4[n * 5 + jq];
        g[0] = (double)v.x; g[1] = (double)v.y; g[2] = (double)v.z; g[3] = (double)v.w;
    }
    if (p0) { g[0] += (double)v0.x; g[1] += (double)v0.y; g[2] += (double)v0.z; g[3] += (double)v0.w; }
    if (p1) { g[0] += (double)v1.x; g[1] += (double)v1.y; g[2] += (double)v1.z; g[3] += (double)v1.w; }
    if (p2) { g[0] += (double)v2.x; g[1] += (double)v2.y; g[2] += (double)v2.z; g[3] += (double)v2.w; }
    if (p3) { g[0] += (double)v3.x; g[1] += (double)v3.y; g[2] += (double)v3.z; g[3] += (double)v3.w; }

    // rare tail: deg > 48 (wave-uniform branch)
    if (e1 - e0 > 48) {
        if (ep < 12) {
            for (int e = e0 + 48 + ep; e < e1; e += 12) {
                int s = __builtin_nontemporal_load(&col[e]);
                float4 v = x4[s * 5 + jq];
                g[0] += (double)v.x; g[1] += (double)v.y;
                g[2] += (double)v.z; g[3] += (double)v.w;
            }
        }
    }

    // fold 12 edge slots down to slot 0 (lanes 0..4 hold g[0..3] = features 4*jq..4*jq+3)
#define FOLD(LIM, DELTA)                                                        \
    {                                                                           \
        int srcl = lane + DELTA; if (srcl > 63) srcl = lane;                    \
        double t0 = __shfl(g[0], srcl, 64);                                     \
        double t1 = __shfl(g[1], srcl, 64);                                     \
        double t2 = __shfl(g[2], srcl, 64);                                     \
        double t3 = __shfl(g[3], srcl, 64);                                     \
        if (ep < (LIM)) { g[0] += t0; g[1] += t1; g[2] += t2; g[3] += t3; }     \
    }
    FOLD(4, 40)   // ep(0..3)  += ep+8
    FOLD(4, 20)   // ep(0..3)  += ep+4
    FOLD(2, 10)   // ep(0..1)  += ep+2
    FOLD(1, 5)    // ep(0)     += ep+1
#undef FOLD

    // cross-lane matvec: out_j = sum_k g_k * W[k][j];  g_k lives at lane k>>2, reg k&3
    int jj = (lane < DH) ? lane : 0;
    double acc = 0.0;
#pragma unroll
    for (int k = 0; k < DH; ++k) {
        double gk = __shfl(g[k & 3], k >> 2, 64);
        acc += gk * (double)Wl[k * DH + jj];
    }

    if (lane < DH) {
        double v = acc * din[n] + (double)b[lane];
        if (mode == 0) {
            float r = fmaxf((float)v, 0.0f);
            xout[(long)n * DH + lane] = (float)((double)r * dout[n]);
        } else {
            xout[(long)n * DH + lane] = (float)v;
        }
    }
}

// ---------------- launch ----------------

static inline size_t align256(size_t x) { return (x + 255) & ~(size_t)255; }

extern "C" void kernel_launch(void* const* d_in, const int* in_sizes, int n_in,
                              void* d_out, int out_size, void* d_ws, size_t ws_size,
                              hipStream_t stream) {
    const float* feat    = (const float*)d_in[0];
    const float* W_start = (const float*)d_in[1];
    const float* b_start = (const float*)d_in[2];
    const float* W_mid   = (const float*)d_in[3];
    const float* b_mid   = (const float*)d_in[4];
    const float* W_final = (const float*)d_in[5];
    const float* b_final = (const float*)d_in[6];
    const int*   src     = (const int*)d_in[7];
    const int*   dst     = (const int*)d_in[8];

    const int N = in_sizes[0];              // 100000
    const int E = in_sizes[7];              // 3200000
    const int L = in_sizes[3] / (DH * DH);  // 18 mid layers

    // workspace carve-up
    char* p = (char*)d_ws;
    double* dout_d = (double*)p; p += align256(sizeof(double) * N);
    double* din_d  = (double*)p; p += align256(sizeof(double) * N);
    double* x0     = (double*)p; p += align256(sizeof(double) * N);
    int* out_deg   = (int*)p;    p += align256(sizeof(int) * N);
    int* in_deg    = (int*)p;    p += align256(sizeof(int) * N);
    int* row_ptr   = (int*)p;    p += align256(sizeof(int) * (N + 1));
    int* cursor    = (int*)p;    p += align256(sizeof(int) * N);
    int* col       = (int*)p;    p += align256(sizeof(int) * E);
    float* xa      = (float*)p;  p += align256(sizeof(float) * N * DH);
    float* xb      = (float*)p;  p += align256(sizeof(float) * N * DH);

    const int BT = 256;
    int grid_n  = (N + BT - 1) / BT;
    int grid_e  = (E + BT - 1) / BT;
    int grid_nw = (N + 3) / 4;              // 1 wave per node, 4 waves per block

    // ---- graph setup (identical work every call) ----
    init_deg<<<grid_n, BT, 0, stream>>>(out_deg, in_deg, N);
    count_deg<<<grid_e, BT, 0, stream>>>(src, dst, out_deg, in_deg, E);
    compute_norm<<<grid_n, BT, 0, stream>>>(out_deg, in_deg, dout_d, din_d, N);
    build_rowptr<<<1, 1024, 0, stream>>>(in_deg, row_ptr, cursor, N, E);
    fill_csr<<<grid_e, BT, 0, stream>>>(src, dst, cursor, col, E);

    // ---- layer 0 (scalar input) ----
    compute_x0<<<grid_n, BT, 0, stream>>>(feat, dout_d, x0, N);
    layer_start<<<grid_nw, BT, 0, stream>>>(x0, row_ptr, col, din_d, dout_d,
                                            W_start, b_start, xa, N);

    // ---- 18 mid layers (ping-pong xa/xb) ----
    float* xin = xa;
    float* xot = xb;
    for (int l = 0; l < L; ++l) {
        layer_mid<<<grid_nw, BT, 0, stream>>>(xin, row_ptr, col, din_d, dout_d,
                                              W_mid + (size_t)l * DH * DH,
                                              b_mid + (size_t)l * DH, xot, N, 0);
        float* t = xin; xin = xot; xot = t;
    }

    // ---- final layer: raw store to d_out ----
    layer_mid<<<grid_nw, BT, 0, stream>>>(xin, row_ptr, col, din_d, dout_d,
                                          W_final, b_final, (float*)d_out, N, 1);
}